// Round 18
// baseline (127.983 us; speedup 1.0000x reference)
//
#include <hip/hip_runtime.h>
#include <hip/hip_bf16.h>
#include <cstdint>
#include <cmath>

#define EPSV 1e-6f
#define PSTR 1183744

typedef __attribute__((ext_vector_type(8))) short bf16x8;
typedef __attribute__((ext_vector_type(4))) float f32x4;

typedef __attribute__((address_space(3))) unsigned int lds_u32;
typedef const __attribute__((address_space(1))) unsigned int g_u32;

__device__ __forceinline__ void load_lds16(const void* g, void* l) {
  __builtin_amdgcn_global_load_lds((g_u32*)g, (lds_u32*)l, 16, 0, 0);
}

__device__ __forceinline__ short f2b(float f) {
  unsigned u = __float_as_uint(f);
  u = (u + 0x7fffu + ((u >> 16) & 1u)) >> 16;   // RNE fp32 -> bf16
  return (short)u;
}

__device__ __forceinline__ bf16x8 cvt8(float4 a, float4 b) {
  bf16x8 v;
  v[0]=f2b(a.x); v[1]=f2b(a.y); v[2]=f2b(a.z); v[3]=f2b(a.w);
  v[4]=f2b(b.x); v[5]=f2b(b.y); v[6]=f2b(b.z); v[7]=f2b(b.w);
  return v;
}

__global__ __launch_bounds__(256) void conv_bf16(
    const float* __restrict__ in, short* __restrict__ out, int n8) {
  const int i = blockIdx.x * 256 + threadIdx.x;
  if (i < n8) {
    float4 a = ((const float4*)in)[2 * i];
    float4 b = ((const float4*)in)[2 * i + 1];
    ((bf16x8*)out)[i] = cvt8(a, b);
  }
}

// Outp[ks][64][N] = Abf[64,K-slice] @ W[N,K-slice]^T   (bf16 MFMA)
// WAVE-AUTONOMOUS deep-DMA pipeline: zero barriers. Each wave owns a
// private LDS region (W strip 16n x 32k fp32 = 2KB; its OWN copy of
// A 64m x 32k bf16 = 4KB; x3 buffers = 18KB/wave, 72KB/block) and a
// private 3-deep vmcnt(6) ledger. The R3..R17 designs all block-convoyed
// at a shared barrier+vmcnt stall (compute slack ~500cyc < ~900cyc HBM
// latency); here 8 independent waves/CU interleave their stalls.
// A-duplication (4x) is L2-hot (xbf=256KB): ~296MB from L2 ~ 9us total.
// Order pinned (rule 18): wait -> SB -> stage(t+2) -> SB -> compute(t).
// Swizzle (rule 21, pre-swizzled global source):
//   W row=128B/8gran: g^(r&7);  A row=64B/4gran: g^((r>>1)&3)  -> 2-way.
template<int KSPLIT, int NT>
__global__ __launch_bounds__(256, 2) void gemm_wave(
    const short* __restrict__ Abf, const float* __restrict__ W,
    float* __restrict__ Outp, int N, int K) {
  __shared__ float Wl[4][3][16 * 32];   // [wave][buf] 2KB
  __shared__ short Al[4][3][64 * 32];   // [wave][buf] 4KB
  const int lane = threadIdx.x & 63;
  const int wv = threadIdx.x >> 6;
  const int lrow = lane & 15, lk = lane >> 4;
  const int bid = blockIdx.x;
  const int ks = bid % KSPLIT;
  const int nblk = (bid / KSPLIT) * 64;
  const int n0 = nblk + wv * 16;         // wave's private 16 W-rows
  const int kbase = ks * (NT * 32);

  f32x4 acc[4];
#pragma unroll
  for (int i = 0; i < 4; ++i) acc[i] = (f32x4){0.f, 0.f, 0.f, 0.f};

  auto stage = [&](int buf, int k0) {
    // W: 2 instr; instr j covers rows 8j..8j+7 (8 x 128B)
#pragma unroll
    for (int j = 0; j < 2; ++j) {
      const int r = j * 8 + (lane >> 3);         // 0..15 (wave-local W row)
      const int g = (lane & 7) ^ (r & 7);
      load_lds16(W + (size_t)(n0 + r) * K + k0 + g * 4,
                 (char*)&Wl[wv][buf][0] + j * 1024);
    }
    // A: 4 instr; instr j covers rows 16j..16j+15 (16 x 64B)
#pragma unroll
    for (int j = 0; j < 4; ++j) {
      const int r = j * 16 + (lane >> 2);        // 0..63 (m row)
      const int g = (lane & 3) ^ ((r >> 1) & 3);
      load_lds16(Abf + (size_t)r * K + k0 + g * 8,
                 (char*)&Al[wv][buf][0] + j * 1024);
    }
  };

  auto compute = [&](int buf) {
    // W frag: row lrow, k-quarter lk (granules 2lk, 2lk+1)
    const float4 wlo = *(const float4*)((const char*)&Wl[wv][buf][0]
                        + lrow * 128 + (((2 * lk)     ^ (lrow & 7)) * 16));
    const float4 whi = *(const float4*)((const char*)&Wl[wv][buf][0]
                        + lrow * 128 + (((2 * lk + 1) ^ (lrow & 7)) * 16));
    const bf16x8 wb = cvt8(wlo, whi);
#pragma unroll
    for (int mf = 0; mf < 4; ++mf) {
      const int ar = mf * 16 + lrow;
      const int ga = lk ^ ((ar >> 1) & 3);
      const bf16x8 av = *(const bf16x8*)((const char*)&Al[wv][buf][0]
                         + ar * 64 + ga * 16);
      acc[mf] = __builtin_amdgcn_mfma_f32_16x16x32_bf16(av, wb, acc[mf], 0, 0, 0);
    }
  };

  // prologue: 2 tiles in flight = 12 loads/wave outstanding
  stage(0, kbase);
  stage(1, kbase + 32);

  for (int t = 0; t < NT; ++t) {
    if (t < NT - 1) asm volatile("s_waitcnt vmcnt(6)");  // tile t landed; t+1 flying
    else            asm volatile("s_waitcnt vmcnt(0)");
    __builtin_amdgcn_sched_barrier(0);
    if (t + 2 <= NT - 1) stage((t + 2) % 3, kbase + (t + 2) * 32);
    __builtin_amdgcn_sched_barrier(0);
    compute(t % 3);
  }

  // C/D layout: col(lane&15)=n, row=(lane>>4)*4+i=m  [m89-verified]
  float* ob = Outp + (size_t)ks * 64 * N + n0 + lrow;
#pragma unroll
  for (int mf = 0; mf < 4; ++mf)
#pragma unroll
    for (int i = 0; i < 4; ++i)
      ob[(size_t)(mf * 16 + lk * 4 + i) * N] = acc[mf][i];
}

__device__ __forceinline__ float block_reduce_sum256(float v, float* red, int t) {
#pragma unroll
  for (int o = 32; o > 0; o >>= 1) v += __shfl_xor(v, o, 64);
  __syncthreads();
  if ((t & 63) == 0) red[t >> 6] = v;
  __syncthreads();
  return red[0] + red[1] + red[2] + red[3];
}

// one block per (b, head); 256 threads. proj = sum of 4 split-K partials.
__global__ __launch_bounds__(256) void state_update(
    const float* __restrict__ pp, const float* __restrict__ h,
    const float* __restrict__ B_prev, const float* __restrict__ x_prev,
    const float* __restrict__ theta_cumsum, const float* __restrict__ A_log,
    const float* __restrict__ B_bias, const float* __restrict__ C_bias,
    float* __restrict__ o_h, float* __restrict__ o_B,
    float* __restrict__ o_xp, float* __restrict__ o_th,
    short* __restrict__ ysbf) {
  const int bid = blockIdx.x;            // b*32 + hd
  const int b = bid >> 5, hd = bid & 31;
  const int t = threadIdx.x;
  const size_t pb = (size_t)b * 18496;
#define PJ(o) (pp[pb + (o)] + pp[PSTR + pb + (o)] + pp[2 * PSTR + pb + (o)] \
             + pp[3 * PSTR + pb + (o)])

  __shared__ float sB[128], sC[128], sBp[128], sXp[128], sXv[128];
  __shared__ float red[8];
  __shared__ float yred[8][128];

  float aval = (t < 128) ? expf(A_log[hd * 128 + t]) : 0.f;
  float brv  = (t < 128) ? PJ(8192 + hd * 128 + t) : 0.f;
  float crv  = (t < 128) ? PJ(12288 + hd * 128 + t) : 0.f;
  if (t < 128) {
    sBp[t] = B_prev[(size_t)bid * 128 + t];
    float xp = PJ(hd * 128 + t);
    sXp[t] = xp;
    o_xp[(size_t)bid * 128 + t] = xp;
    sXv[t] = x_prev[(size_t)bid * 128 + t];
  }
  float sumA  = block_reduce_sum256(aval, red, t);
  float sumB2 = block_reduce_sum256(brv * brv, red, t);
  float sumC2 = block_reduce_sum256(crv * crv, red, t);

  const float dt_raw  = PJ(16384 + hd);
  const float lam_raw = PJ(16416 + hd);
  const float dt  = (dt_raw > 20.f) ? dt_raw : log1pf(expf(dt_raw));
  const float lam = 1.f / (1.f + expf(-lam_raw));
  const float A     = -sumA * (1.f / 128.f);
  const float alpha = expf(dt * A);
  const float beta  = (1.f - lam) * dt * alpha;
  const float gamma = lam * dt;
  const float rb = rsqrtf(sumB2 * (1.f / 128.f) + EPSV);
  const float rc = rsqrtf(sumC2 * (1.f / 128.f) + EPSV);

  if (t < 64) {
    float b0 = PJ(8192 + hd * 128 + 2 * t);
    float b1 = PJ(8192 + hd * 128 + 2 * t + 1);
    float c0 = PJ(12288 + hd * 128 + 2 * t);
    float c1 = PJ(12288 + hd * 128 + 2 * t + 1);
    b0 = b0 * rb + B_bias[hd * 128 + 2 * t];
    b1 = b1 * rb + B_bias[hd * 128 + 2 * t + 1];
    c0 = c0 * rc + C_bias[hd * 128 + 2 * t];
    c1 = c1 * rc + C_bias[hd * 128 + 2 * t + 1];
    const float th = theta_cumsum[(size_t)bid * 64 + t]
                   + PJ(16448 + hd * 64 + t) * dt;
    o_th[(size_t)bid * 64 + t] = th;
    const float cth = cosf(th), sth = sinf(th);
    const float nb0 = b0 * cth - b1 * sth, nb1 = b0 * sth + b1 * cth;
    const float nc0 = c0 * cth - c1 * sth, nc1 = c0 * sth + c1 * cth;
    sB[2 * t] = nb0; sB[2 * t + 1] = nb1;
    sC[2 * t] = nc0; sC[2 * t + 1] = nc1;
    o_B[(size_t)bid * 128 + 2 * t] = nb0;
    o_B[(size_t)bid * 128 + 2 * t + 1] = nb1;
  }
  __syncthreads();

  const int p4 = t & 31, nb = t >> 5;
  const float4 xp4 = *(const float4*)&sXp[p4 * 4];
  const float4 xv4 = *(const float4*)&sXv[p4 * 4];
  const size_t hbase = (size_t)bid * 16384;
  float4 ya = {0.f, 0.f, 0.f, 0.f};
  for (int n = nb; n < 128; n += 8) {
    const float4 hv = *(const float4*)&h[hbase + n * 128 + p4 * 4];
    const float cb = gamma * sB[n];
    const float cp = beta * sBp[n];
    float4 hn;
    hn.x = alpha * hv.x + cp * xv4.x + cb * xp4.x;
    hn.y = alpha * hv.y + cp * xv4.y + cb * xp4.y;
    hn.z = alpha * hv.z + cp * xv4.z + cb * xp4.z;
    hn.w = alpha * hv.w + cp * xv4.w + cb * xp4.w;
    *(float4*)&o_h[hbase + n * 128 + p4 * 4] = hn;
    const float cn = sC[n];
    ya.x += cn * hn.x; ya.y += cn * hn.y; ya.z += cn * hn.z; ya.w += cn * hn.w;
  }
  *(float4*)&yred[nb][p4 * 4] = ya;
  __syncthreads();
  if (t < 128) {
    float y = 0.f;
#pragma unroll
    for (int j = 0; j < 8; ++j) y += yred[j][t];
    const float zv = PJ(4096 + hd * 128 + t);
    const float sig = 1.f / (1.f + expf(-zv));
    ysbf[(size_t)b * 4096 + hd * 128 + t] = f2b(y * zv * sig);
  }
#undef PJ
}

// y[64][2048] = sum over 16 K-split partials
__global__ __launch_bounds__(256) void reduce_y(
    const float* __restrict__ yp, float* __restrict__ y, int n4) {
  const int i = blockIdx.x * 256 + threadIdx.x;
  if (i < n4) {
    float4 s = ((const float4*)yp)[i];
#pragma unroll
    for (int k = 1; k < 16; ++k) {
      float4 t = ((const float4*)(yp + (size_t)k * 131072))[i];
      s.x += t.x; s.y += t.y; s.z += t.z; s.w += t.w;
    }
    ((float4*)y)[i] = s;
  }
}

extern "C" void kernel_launch(void* const* d_in, const int* in_sizes, int n_in,
                              void* d_out, int out_size, void* d_ws, size_t ws_size,
                              hipStream_t stream) {
  const float* x            = (const float*)d_in[0];
  const float* h            = (const float*)d_in[1];
  const float* B_prev       = (const float*)d_in[2];
  const float* x_prev       = (const float*)d_in[3];
  const float* theta_cumsum = (const float*)d_in[4];
  const float* W_in         = (const float*)d_in[5];
  const float* A_log        = (const float*)d_in[6];
  const float* B_bias       = (const float*)d_in[7];
  const float* C_bias       = (const float*)d_in[8];
  const float* W_out        = (const float*)d_in[9];

  float* out  = (float*)d_out;
  float* o_y  = out;                        // 64*2048
  float* o_h  = out + 131072;               // 64*32*128*128
  float* o_B  = o_h + 33554432;             // 64*32*128
  float* o_xp = o_B + 262144;               // 64*32*128
  float* o_th = o_xp + 262144;              // 64*32*64

  // ws layout
  float* pp   = (float*)d_ws;               // 4 x PSTR fp32 split-K partials
  float* yp   = pp;                         // 16 x 131072 fp32 (reuse after SU)
  short* xbf  = (short*)(pp + 4 * PSTR);    // 64*2048 bf16
  short* ysbf = xbf + 131072;               // 64*4096 bf16

  // 1) x -> bf16
  conv_bf16<<<dim3(64), dim3(256), 0, stream>>>(x, xbf, 16384);
  // 2) proj partials = xbf @ W_in^T  (N=18496, K=2048, KSPLIT=4, NT=16)
  gemm_wave<4, 16><<<dim3(289 * 4), dim3(256), 0, stream>>>(
      xbf, W_in, pp, 18496, 2048);
  // 3) fused state update (sums 4 partials at load)
  state_update<<<dim3(2048), dim3(256), 0, stream>>>(
      pp, h, B_prev, x_prev, theta_cumsum, A_log, B_bias, C_bias,
      o_h, o_B, o_xp, o_th, ysbf);
  // 4) y partials = ysbf @ W_out^T   (N=2048, K=4096, KSPLIT=16, NT=8)
  gemm_wave<16, 8><<<dim3(32 * 16), dim3(256), 0, stream>>>(
      ysbf, W_out, yp, 2048, 4096);
  // 5) final y reduce
  reduce_y<<<dim3(128), dim3(256), 0, stream>>>(yp, o_y, 32768);
}

// Round 19
// 126.935 us; speedup vs baseline: 1.0083x; 1.0083x over previous
//
#include <hip/hip_runtime.h>
#include <hip/hip_bf16.h>
#include <cstdint>
#include <cmath>

#define EPSV 1e-6f
#define PSTR 1183744

typedef __attribute__((ext_vector_type(8))) short bf16x8;
typedef __attribute__((ext_vector_type(4))) float f32x4;

typedef __attribute__((address_space(3))) unsigned int lds_u32;
typedef const __attribute__((address_space(1))) unsigned int g_u32;

__device__ __forceinline__ void load_lds16(const void* g, void* l) {
  __builtin_amdgcn_global_load_lds((g_u32*)g, (lds_u32*)l, 16, 0, 0);
}

__device__ __forceinline__ short f2b(float f) {
  unsigned u = __float_as_uint(f);
  u = (u + 0x7fffu + ((u >> 16) & 1u)) >> 16;   // RNE fp32 -> bf16
  return (short)u;
}

__device__ __forceinline__ bf16x8 cvt8(float4 a, float4 b) {
  bf16x8 v;
  v[0]=f2b(a.x); v[1]=f2b(a.y); v[2]=f2b(a.z); v[3]=f2b(a.w);
  v[4]=f2b(b.x); v[5]=f2b(b.y); v[6]=f2b(b.z); v[7]=f2b(b.w);
  return v;
}

__global__ __launch_bounds__(256) void conv_bf16(
    const float* __restrict__ in, short* __restrict__ out, int n8) {
  const int i = blockIdx.x * 256 + threadIdx.x;
  if (i < n8) {
    float4 a = ((const float4*)in)[2 * i];
    float4 b = ((const float4*)in)[2 * i + 1];
    ((bf16x8*)out)[i] = cvt8(a, b);
  }
}

// GEMM1: Outp[ks][64][N] = Abf[64,Kslice] @ W[N,Kslice]^T, BN=128 tile.
// R17 pipeline (3-buf DMA, clobber-free counted vmcnt), but 128 N-rows
// per block: halves the invariant A-duplication term (A bytes =
// N/BN x K x 128B: 74MB -> 38MB) -> staged total 226 -> 190 MB at the
// observed ~4.3 TB/s DMA rate. 60KB LDS -> 2 blocks/CU. 5 loads/stage
// -> ledger vmcnt(5), prologue 10. N=18496=144x128+64: staging rows
// clamp to N-1, stores guarded n<N.
template<int KSPLIT, int NT>
__global__ __launch_bounds__(256, 2) void gemm_t128(
    const short* __restrict__ Abf, const float* __restrict__ W,
    float* __restrict__ Outp, int N, int K) {
  __shared__ float Wlds[3][128 * 32];   // 16KB/buf, row=128B, swz g^(r&7)
  __shared__ short Alds[3][64 * 32];    // 4KB/buf, row=64B, swz g^((r>>1)&3)
  const int lane = threadIdx.x & 63;
  const int wv = threadIdx.x >> 6;
  const int lrow = lane & 15, lk = lane >> 4;
  const int bid = blockIdx.x;
  const int ks = bid % KSPLIT;
  const int n0 = (bid / KSPLIT) * 128;
  const int kbase = ks * (NT * 32);

  f32x4 acc[2][4];
#pragma unroll
  for (int a = 0; a < 2; ++a)
#pragma unroll
    for (int b = 0; b < 4; ++b) acc[a][b] = (f32x4){0.f, 0.f, 0.f, 0.f};

  auto stage = [&](int buf, int k0) {
    // W: 4 loads/thread; chunk c = wv*4+j covers rows 8c..8c+7 (8 x 128B)
#pragma unroll
    for (int j = 0; j < 4; ++j) {
      const int c = wv * 4 + j;
      const int r = c * 8 + (lane >> 3);           // 0..127
      const int g = (lane & 7) ^ (r & 7);
      int gr = n0 + r; if (gr > N - 1) gr = N - 1; // clamp (reads only)
      load_lds16(W + (size_t)gr * K + k0 + g * 4,
                 (char*)&Wlds[buf][0] + c * 1024);
    }
    // A: 1 load/thread; chunk wv covers rows 16wv..16wv+15 (16 x 64B)
    {
      const int r = wv * 16 + (lane >> 2);         // 0..63
      const int g = (lane & 3) ^ ((r >> 1) & 3);
      load_lds16(Abf + (size_t)r * K + k0 + g * 8,
                 (char*)&Alds[buf][0] + wv * 1024);
    }
  };

  auto compute = [&](int buf) {
#pragma unroll
    for (int mfw = 0; mfw < 2; ++mfw) {
      const int wr = wv * 32 + mfw * 16 + lrow;    // W local row 0..127
      const float4 wlo = *(const float4*)((const char*)&Wlds[buf][0]
                          + wr * 128 + (((2 * lk)     ^ (wr & 7)) * 16));
      const float4 whi = *(const float4*)((const char*)&Wlds[buf][0]
                          + wr * 128 + (((2 * lk + 1) ^ (wr & 7)) * 16));
      const bf16x8 wb = cvt8(wlo, whi);
#pragma unroll
      for (int mfa = 0; mfa < 4; ++mfa) {
        const int ar = mfa * 16 + lrow;
        const int ga = lk ^ ((ar >> 1) & 3);
        const bf16x8 av = *(const bf16x8*)((const char*)&Alds[buf][0]
                           + ar * 64 + ga * 16);
        acc[mfw][mfa] = __builtin_amdgcn_mfma_f32_16x16x32_bf16(av, wb, acc[mfw][mfa], 0, 0, 0);
      }
    }
  };

  // prologue: 2 tiles in flight = 10 loads/thread outstanding
  stage(0, kbase);
  stage(1, kbase + 32);

  for (int t = 0; t < NT; ++t) {
    if (t < NT - 1) asm volatile("s_waitcnt vmcnt(5)");  // tile t landed; t+1 flying
    else            asm volatile("s_waitcnt vmcnt(0)");
    __builtin_amdgcn_sched_barrier(0);
    __builtin_amdgcn_s_barrier();   // tile t visible; all waves past compute(t-1)
    __builtin_amdgcn_sched_barrier(0);
    compute(t % 3);
    if (t + 2 <= NT - 1) stage((t + 2) % 3, kbase + (t + 2) * 32);
  }

  // C/D: col(lane&15)=n-in-frag, row=(lane>>4)*4+i=m  [m89-verified]
  float* ob = Outp + (size_t)ks * 64 * N;
#pragma unroll
  for (int mfw = 0; mfw < 2; ++mfw) {
    const int n = n0 + wv * 32 + mfw * 16 + lrow;
    if (n < N) {
#pragma unroll
      for (int mfa = 0; mfa < 4; ++mfa)
#pragma unroll
        for (int i = 0; i < 4; ++i)
          ob[(size_t)(mfa * 16 + lk * 4 + i) * N + n] = acc[mfw][mfa][i];
    }
  }
}

// GEMM2 (proven R17 template): BN=64, both operands DMA-staged.
template<int KSPLIT, int NT>
__global__ __launch_bounds__(256, 2) void gemm_wlds(
    const short* __restrict__ Abf, const float* __restrict__ W,
    float* __restrict__ Outp, int N, int K) {
  __shared__ float Wlds[3][64 * 64];
  __shared__ short Alds[3][64 * 64];
  const int lane = threadIdx.x & 63;
  const int wv = threadIdx.x >> 6;
  const int lrow = lane & 15, lk = lane >> 4;
  const int bid = blockIdx.x;
  const int ks = bid % KSPLIT;
  const int nblk = (bid / KSPLIT) * 64;
  const int kbase = ks * (NT * 64);

  f32x4 acc[4];
#pragma unroll
  for (int i = 0; i < 4; ++i) acc[i] = (f32x4){0.f, 0.f, 0.f, 0.f};

  auto stage = [&](int buf, int k0) {
#pragma unroll
    for (int j = 0; j < 4; ++j) {
      const int c = wv * 4 + j;
      const int r = c * 4 + (lane >> 4);
      const int g = (lane & 15) ^ (r & 15);
      load_lds16(W + (size_t)(nblk + r) * K + k0 + g * 4,
                 (char*)&Wlds[buf][0] + c * 1024);
    }
#pragma unroll
    for (int j = 0; j < 2; ++j) {
      const int c = wv * 2 + j;
      const int r = c * 8 + (lane >> 3);
      const int g = (lane & 7) ^ (r & 7);
      load_lds16(Abf + (size_t)r * K + k0 + g * 8,
                 (char*)&Alds[buf][0] + c * 1024);
    }
  };

  auto compute = [&](int buf) {
    const int wr = wv * 16 + lrow;
#pragma unroll
    for (int kc = 0; kc < 2; ++kc) {
      const int g0 = kc * 8 + lk * 2;
      const float4 wlo = *(const float4*)((const char*)&Wlds[buf][0]
                          + wr * 256 + ((g0 ^ (lrow & 15)) * 16));
      const float4 whi = *(const float4*)((const char*)&Wlds[buf][0]
                          + wr * 256 + (((g0 + 1) ^ (lrow & 15)) * 16));
      const bf16x8 wb = cvt8(wlo, whi);
#pragma unroll
      for (int mf = 0; mf < 4; ++mf) {
        const int ar = mf * 16 + lrow;
        const int ga = ((kc << 2) | lk) ^ (ar & 7);
        const bf16x8 av = *(const bf16x8*)((const char*)&Alds[buf][0]
                           + ar * 128 + ga * 16);
        acc[mf] = __builtin_amdgcn_mfma_f32_16x16x32_bf16(av, wb, acc[mf], 0, 0, 0);
      }
    }
  };

  stage(0, kbase);
  stage(1, kbase + 64);

  for (int t = 0; t < NT; ++t) {
    if (t < NT - 1) asm volatile("s_waitcnt vmcnt(6)");
    else            asm volatile("s_waitcnt vmcnt(0)");
    __builtin_amdgcn_sched_barrier(0);
    __builtin_amdgcn_s_barrier();
    __builtin_amdgcn_sched_barrier(0);
    compute(t % 3);
    if (t + 2 <= NT - 1) stage((t + 2) % 3, kbase + (t + 2) * 64);
  }

  float* ob = Outp + (size_t)ks * 64 * N + nblk + wv * 16 + lrow;
#pragma unroll
  for (int mf = 0; mf < 4; ++mf)
#pragma unroll
    for (int i = 0; i < 4; ++i)
      ob[(size_t)(mf * 16 + lk * 4 + i) * N] = acc[mf][i];
}

__device__ __forceinline__ float block_reduce_sum256(float v, float* red, int t) {
#pragma unroll
  for (int o = 32; o > 0; o >>= 1) v += __shfl_xor(v, o, 64);
  __syncthreads();
  if ((t & 63) == 0) red[t >> 6] = v;
  __syncthreads();
  return red[0] + red[1] + red[2] + red[3];
}

// one block per (b, head); 256 threads. proj = sum of 4 split-K partials.
__global__ __launch_bounds__(256) void state_update(
    const float* __restrict__ pp, const float* __restrict__ h,
    const float* __restrict__ B_prev, const float* __restrict__ x_prev,
    const float* __restrict__ theta_cumsum, const float* __restrict__ A_log,
    const float* __restrict__ B_bias, const float* __restrict__ C_bias,
    float* __restrict__ o_h, float* __restrict__ o_B,
    float* __restrict__ o_xp, float* __restrict__ o_th,
    short* __restrict__ ysbf) {
  const int bid = blockIdx.x;            // b*32 + hd
  const int b = bid >> 5, hd = bid & 31;
  const int t = threadIdx.x;
  const size_t pb = (size_t)b * 18496;
#define PJ(o) (pp[pb + (o)] + pp[PSTR + pb + (o)] + pp[2 * PSTR + pb + (o)] \
             + pp[3 * PSTR + pb + (o)])

  __shared__ float sB[128], sC[128], sBp[128], sXp[128], sXv[128];
  __shared__ float red[8];
  __shared__ float yred[8][128];

  float aval = (t < 128) ? expf(A_log[hd * 128 + t]) : 0.f;
  float brv  = (t < 128) ? PJ(8192 + hd * 128 + t) : 0.f;
  float crv  = (t < 128) ? PJ(12288 + hd * 128 + t) : 0.f;
  if (t < 128) {
    sBp[t] = B_prev[(size_t)bid * 128 + t];
    float xp = PJ(hd * 128 + t);
    sXp[t] = xp;
    o_xp[(size_t)bid * 128 + t] = xp;
    sXv[t] = x_prev[(size_t)bid * 128 + t];
  }
  float sumA  = block_reduce_sum256(aval, red, t);
  float sumB2 = block_reduce_sum256(brv * brv, red, t);
  float sumC2 = block_reduce_sum256(crv * crv, red, t);

  const float dt_raw  = PJ(16384 + hd);
  const float lam_raw = PJ(16416 + hd);
  const float dt  = (dt_raw > 20.f) ? dt_raw : log1pf(expf(dt_raw));
  const float lam = 1.f / (1.f + expf(-lam_raw));
  const float A     = -sumA * (1.f / 128.f);
  const float alpha = expf(dt * A);
  const float beta  = (1.f - lam) * dt * alpha;
  const float gamma = lam * dt;
  const float rb = rsqrtf(sumB2 * (1.f / 128.f) + EPSV);
  const float rc = rsqrtf(sumC2 * (1.f / 128.f) + EPSV);

  if (t < 64) {
    float b0 = PJ(8192 + hd * 128 + 2 * t);
    float b1 = PJ(8192 + hd * 128 + 2 * t + 1);
    float c0 = PJ(12288 + hd * 128 + 2 * t);
    float c1 = PJ(12288 + hd * 128 + 2 * t + 1);
    b0 = b0 * rb + B_bias[hd * 128 + 2 * t];
    b1 = b1 * rb + B_bias[hd * 128 + 2 * t + 1];
    c0 = c0 * rc + C_bias[hd * 128 + 2 * t];
    c1 = c1 * rc + C_bias[hd * 128 + 2 * t + 1];
    const float th = theta_cumsum[(size_t)bid * 64 + t]
                   + PJ(16448 + hd * 64 + t) * dt;
    o_th[(size_t)bid * 64 + t] = th;
    const float cth = cosf(th), sth = sinf(th);
    const float nb0 = b0 * cth - b1 * sth, nb1 = b0 * sth + b1 * cth;
    const float nc0 = c0 * cth - c1 * sth, nc1 = c0 * sth + c1 * cth;
    sB[2 * t] = nb0; sB[2 * t + 1] = nb1;
    sC[2 * t] = nc0; sC[2 * t + 1] = nc1;
    o_B[(size_t)bid * 128 + 2 * t] = nb0;
    o_B[(size_t)bid * 128 + 2 * t + 1] = nb1;
  }
  __syncthreads();

  const int p4 = t & 31, nb = t >> 5;
  const float4 xp4 = *(const float4*)&sXp[p4 * 4];
  const float4 xv4 = *(const float4*)&sXv[p4 * 4];
  const size_t hbase = (size_t)bid * 16384;
  float4 ya = {0.f, 0.f, 0.f, 0.f};
  for (int n = nb; n < 128; n += 8) {
    const float4 hv = *(const float4*)&h[hbase + n * 128 + p4 * 4];
    const float cb = gamma * sB[n];
    const float cp = beta * sBp[n];
    float4 hn;
    hn.x = alpha * hv.x + cp * xv4.x + cb * xp4.x;
    hn.y = alpha * hv.y + cp * xv4.y + cb * xp4.y;
    hn.z = alpha * hv.z + cp * xv4.z + cb * xp4.z;
    hn.w = alpha * hv.w + cp * xv4.w + cb * xp4.w;
    *(float4*)&o_h[hbase + n * 128 + p4 * 4] = hn;
    const float cn = sC[n];
    ya.x += cn * hn.x; ya.y += cn * hn.y; ya.z += cn * hn.z; ya.w += cn * hn.w;
  }
  *(float4*)&yred[nb][p4 * 4] = ya;
  __syncthreads();
  if (t < 128) {
    float y = 0.f;
#pragma unroll
    for (int j = 0; j < 8; ++j) y += yred[j][t];
    const float zv = PJ(4096 + hd * 128 + t);
    const float sig = 1.f / (1.f + expf(-zv));
    ysbf[(size_t)b * 4096 + hd * 128 + t] = f2b(y * zv * sig);
  }
#undef PJ
}

// y[64][2048] = sum over 16 K-split partials
__global__ __launch_bounds__(256) void reduce_y(
    const float* __restrict__ yp, float* __restrict__ y, int n4) {
  const int i = blockIdx.x * 256 + threadIdx.x;
  if (i < n4) {
    float4 s = ((const float4*)yp)[i];
#pragma unroll
    for (int k = 1; k < 16; ++k) {
      float4 t = ((const float4*)(yp + (size_t)k * 131072))[i];
      s.x += t.x; s.y += t.y; s.z += t.z; s.w += t.w;
    }
    ((float4*)y)[i] = s;
  }
}

extern "C" void kernel_launch(void* const* d_in, const int* in_sizes, int n_in,
                              void* d_out, int out_size, void* d_ws, size_t ws_size,
                              hipStream_t stream) {
  const float* x            = (const float*)d_in[0];
  const float* h            = (const float*)d_in[1];
  const float* B_prev       = (const float*)d_in[2];
  const float* x_prev       = (const float*)d_in[3];
  const float* theta_cumsum = (const float*)d_in[4];
  const float* W_in         = (const float*)d_in[5];
  const float* A_log        = (const float*)d_in[6];
  const float* B_bias       = (const float*)d_in[7];
  const float* C_bias       = (const float*)d_in[8];
  const float* W_out        = (const float*)d_in[9];

  float* out  = (float*)d_out;
  float* o_y  = out;                        // 64*2048
  float* o_h  = out + 131072;               // 64*32*128*128
  float* o_B  = o_h + 33554432;             // 64*32*128
  float* o_xp = o_B + 262144;               // 64*32*128
  float* o_th = o_xp + 262144;              // 64*32*64

  // ws layout
  float* pp   = (float*)d_ws;               // 4 x PSTR fp32 split-K partials
  float* yp   = pp;                         // 16 x 131072 fp32 (reuse after SU)
  short* xbf  = (short*)(pp + 4 * PSTR);    // 64*2048 bf16
  short* ysbf = xbf + 131072;               // 64*4096 bf16

  // 1) x -> bf16
  conv_bf16<<<dim3(64), dim3(256), 0, stream>>>(x, xbf, 16384);
  // 2) proj partials = xbf @ W_in^T  (N=18496, KSPLIT=4, NT=16, BN=128)
  //    145 N-blocks (144 full + 1 half) x 4 = 580 blocks
  gemm_t128<4, 16><<<dim3(145 * 4), dim3(256), 0, stream>>>(
      xbf, W_in, pp, 18496, 2048);
  // 3) fused state update (sums 4 partials at load)
  state_update<<<dim3(2048), dim3(256), 0, stream>>>(
      pp, h, B_prev, x_prev, theta_cumsum, A_log, B_bias, C_bias,
      o_h, o_B, o_xp, o_th, ysbf);
  // 4) y partials = ysbf @ W_out^T   (N=2048, K=4096, KSPLIT=16, NT=4)
  gemm_wlds<16, 4><<<dim3(32 * 16), dim3(256), 0, stream>>>(
      ysbf, W_out, yp, 2048, 4096);
  // 5) final y reduce
  reduce_y<<<dim3(128), dim3(256), 0, stream>>>(yp, o_y, 32768);
}